// Round 4
// baseline (183.829 us; speedup 1.0000x reference)
//
#include <hip/hip_runtime.h>
#include <hip/hip_bf16.h>

typedef __hip_bfloat16 bf16;
typedef __attribute__((ext_vector_type(8))) short short8;
typedef __attribute__((ext_vector_type(4))) float f32x4;

#define DDIM 1024
#define SEQ  4096
#define NB   4
#define MTOT (NB*SEQ)   // 16384 rows

static __device__ __forceinline__ unsigned short f2bf(float f) {
    __hip_bfloat16 h = __float2bfloat16(f);
    unsigned short u; __builtin_memcpy(&u, &h, 2); return u;
}
static __device__ __forceinline__ float bf2f(unsigned short u) {
    __hip_bfloat16 h; __builtin_memcpy(&h, &u, 2); return __bfloat162float(h);
}

// ---------------------------------------------------------------- cast weights
__global__ __launch_bounds__(256) void cast_w_kernel(
    const float* __restrict__ w1, const float* __restrict__ w2,
    unsigned short* __restrict__ w1b, unsigned short* __restrict__ w2b)
{
    size_t idx = ((size_t)blockIdx.x*256 + threadIdx.x) * 4;   // grid 1024 -> 1M elems
    float4 a = *(const float4*)(w1 + idx);
    ushort4 o; o.x=f2bf(a.x); o.y=f2bf(a.y); o.z=f2bf(a.z); o.w=f2bf(a.w);
    *(ushort4*)(w1b + idx) = o;
    float4 b = *(const float4*)(w2 + idx);
    o.x=f2bf(b.x); o.y=f2bf(b.y); o.z=f2bf(b.z); o.w=f2bf(b.w);
    *(ushort4*)(w2b + idx) = o;
}

// ------------------------------------------------------- column sum of x (per batch)
__global__ __launch_bounds__(256) void colsum_partial_kernel(
    const float* __restrict__ x, float* __restrict__ partial)
{
    int d  = blockIdx.x*256 + threadIdx.x;
    int b  = blockIdx.y;
    int sl = blockIdx.z;
    const float* p = x + ((size_t)b*SEQ + (size_t)sl*128)*DDIM + d;
    float s = 0.f;
    #pragma unroll 4
    for (int i = 0; i < 128; ++i) s += p[(size_t)i*DDIM];
    partial[((size_t)sl*NB + b)*DDIM + d] = s;
}

__global__ __launch_bounds__(256) void colsum_reduce_kernel(
    const float* __restrict__ partial, float* __restrict__ xsum)
{
    int d = blockIdx.x*256 + threadIdx.x;
    int b = blockIdx.y;
    float s = 0.f;
    #pragma unroll
    for (int sl = 0; sl < 32; ++sl) s += partial[((size_t)sl*NB + b)*DDIM + d];
    xsum[b*DDIM + d] = s;
}

// ------------------------------------------------------- small matvec: vout = vin @ W^T
__global__ __launch_bounds__(256) void matvec_kernel(
    const float* __restrict__ W, const float* __restrict__ vin, float* __restrict__ vout)
{
    int b = blockIdx.y;
    int g = threadIdx.x >> 4;
    int t = threadIdx.x & 15;
    int e = blockIdx.x*16 + g;
    const float* w = W + (size_t)e*DDIM;
    const float* v = vin + b*DDIM;
    float s = 0.f;
    for (int k = t; k < DDIM; k += 16) s += w[k]*v[k];
    #pragma unroll
    for (int o = 8; o; o >>= 1) s += __shfl_down(s, o, 16);
    if (t == 0) vout[b*DDIM + e] = s;
}

// ------------------------------------------------------- LN1: x1 = LN(x + attnvec) -> bf16
__global__ __launch_bounds__(256) void ln1_kernel(
    const float* __restrict__ x, const float* __restrict__ avec,
    const float* __restrict__ g1, const float* __restrict__ b1,
    unsigned short* __restrict__ x1b)
{
    int row = blockIdx.x;
    int b   = row >> 12;          // row / SEQ
    int tid = threadIdx.x;
    const float4* xr = (const float4*)(x + (size_t)row*DDIM);
    const float4* av = (const float4*)(avec + (size_t)b*DDIM);
    float4 xv = xr[tid], a4 = av[tid];
    float y0 = xv.x+a4.x, y1 = xv.y+a4.y, y2 = xv.z+a4.z, y3 = xv.w+a4.w;
    float s  = y0+y1+y2+y3;
    float ss = y0*y0+y1*y1+y2*y2+y3*y3;
    #pragma unroll
    for (int o = 32; o; o >>= 1) { s += __shfl_down(s,o,64); ss += __shfl_down(ss,o,64); }
    __shared__ float red[8];
    if ((tid&63) == 0) { red[tid>>6] = s; red[4+(tid>>6)] = ss; }
    __syncthreads();
    float St = red[0]+red[1]+red[2]+red[3];
    float Sq = red[4]+red[5]+red[6]+red[7];
    float mu = St*(1.0f/DDIM);
    float rs = rsqrtf(Sq*(1.0f/DDIM) - mu*mu + 1e-5f);
    float4 g4 = ((const float4*)g1)[tid];
    float4 bb = ((const float4*)b1)[tid];
    ushort4 o;
    o.x = f2bf((y0-mu)*rs*g4.x + bb.x);
    o.y = f2bf((y1-mu)*rs*g4.y + bb.y);
    o.z = f2bf((y2-mu)*rs*g4.z + bb.z);
    o.w = f2bf((y3-mu)*rs*g4.w + bb.w);
    *(ushort4*)(x1b + (size_t)row*DDIM + tid*4) = o;
}

// ------------------------------------------------------- 256x256 8-phase MFMA GEMM
// C = A @ W^T ; MODE 1: outb = bf16(gelu(C+bias)) ; MODE 2: outf = C + bias + bf16resid
// 8 waves (2Mx4N), BK=64, 2 K-tiles/iter, 128 KB dynamic LDS, counted vmcnt(4) gates.
template<int MODE>
__global__ __launch_bounds__(512, 2) void gemm256p8_kernel(
    const bf16* __restrict__ A, const bf16* __restrict__ Bw,
    const float* __restrict__ bias, const unsigned short* __restrict__ resid,
    unsigned short* __restrict__ outb, float* __restrict__ outf)
{
    constexpr int K = 1024, N = 1024;
    extern __shared__ char smem[];                 // 128 KB: 8 regions of 16 KB
    const int tid  = threadIdx.x;
    const int wave = tid >> 6, lane = tid & 63;

    // T1: bijective XCD swizzle. grid 256 = 64 M-tiles x 4 N-tiles; 32 blocks/XCD (8M x 4N).
    int bid = blockIdx.x;
    int swz = (bid & 7) * 32 + (bid >> 3);
    const size_t bm = (size_t)(swz >> 2) * 256;
    const size_t bn = (size_t)(swz & 3) * 256;

    const int wm = wave >> 2;      // 0..1 (128-row half)
    const int wn = wave & 3;       // 0..3 (64-col strip)

    // LDS region: [d][mat 0=A/1=B][half]  16 KB each = 128 rows x 64 k bf16
    auto reg_ = [&](int d, int mat, int h) -> char* {
        return smem + (((d << 2) | (mat << 1) | h) << 14);
    };

    // ---- staging (rule #21): linear LDS dest, inverse-swizzled global source.
    // load g covers rows g*64 + (tid>>3); phys 16B-slot = tid&7; logical slot = phys ^ (row&7).
    const int srow = tid >> 3;
    const int skel = (((tid & 7) ^ ((tid >> 3) & 7)) << 3);   // k element offset

    auto stage_half = [&](char* dst, const bf16* srcbase, int kt) {   // 2 loads/wave
        #pragma unroll
        for (int g = 0; g < 2; ++g) {
            const bf16* gp = srcbase + (size_t)(g*64 + srow) * K + kt*64 + skel;
            __builtin_amdgcn_global_load_lds(
                (const __attribute__((address_space(1))) void*)gp,
                (__attribute__((address_space(3))) void*)(dst + g*8192 + wave*1024),
                16, 0, 0);
        }
    };

    // ---- fragment reads (swizzled ds_read_b128): slot(kk) = kk*4 + (lane>>4), phys = slot^(lr&7)
    const int fr = lane & 15;
    const int fs = lane >> 4;

    short8 a0[8], a1[8], b0[4], b1[4];
    f32x4 acc[8][4] = {};

    auto rdA = [&](int d, int kk, short8* dstf) {
        const char* base = reg_(d, 0, wm);
        #pragma unroll
        for (int mf = 0; mf < 8; ++mf) {
            int lr = mf*16 + fr;
            int phys = (kk*4 + fs) ^ (lr & 7);
            dstf[mf] = *(const short8*)(base + lr*128 + phys*16);
        }
    };
    auto rdB = [&](int d, int kk, short8* dstf) {
        const char* base = reg_(d, 1, wn >> 1);
        #pragma unroll
        for (int nf = 0; nf < 4; ++nf) {
            int lr = (wn & 1)*64 + nf*16 + fr;
            int phys = (kk*4 + fs) ^ (lr & 7);
            dstf[nf] = *(const short8*)(base + lr*128 + phys*16);
        }
    };
    auto mm = [&](short8* af, short8* bf_, int nbase) {   // 16 MFMA
        __builtin_amdgcn_s_setprio(1);
        #pragma unroll
        for (int mf = 0; mf < 8; ++mf)
            #pragma unroll
            for (int nn = 0; nn < 2; ++nn)
                acc[mf][nbase+nn] = __builtin_amdgcn_mfma_f32_16x16x32_bf16(
                    af[mf], bf_[nbase+nn], acc[mf][nbase+nn], 0, 0, 0);
        __builtin_amdgcn_s_setprio(0);
    };

    #define PH_BAR __builtin_amdgcn_s_barrier()
    #define LGK0  asm volatile("s_waitcnt lgkmcnt(0)" ::: "memory")
    #define VM4   asm volatile("s_waitcnt vmcnt(4)"  ::: "memory")

    const bf16* Ab = A  + bm * K;
    const bf16* Bb = Bw + bn * K;

    // prologue: kt0 {A0,A1,B0,B1}, kt1 {A0,A1}; then drain kt0 (vmcnt(4)).
    stage_half(reg_(0,0,0), Ab,         0);
    stage_half(reg_(0,0,1), Ab + 128*K, 0);
    stage_half(reg_(0,1,0), Bb,         0);
    stage_half(reg_(0,1,1), Bb + 128*K, 0);
    stage_half(reg_(1,0,0), Ab,         1);
    stage_half(reg_(1,0,1), Ab + 128*K, 1);
    VM4;                                  // kt0 landed; kt1.A in flight
    PH_BAR;

    for (int i = 0; i < 8; ++i) {         // 2 K-tiles per iteration, 16 K-tiles total
        const int kt1 = 2*i + 1;
        const int kt2 = (2*i + 2) & 15;   // wrap at tail: redundant re-stage, race-free
        const int kt3 = (2*i + 3) & 15;
        // phase 0: compute kt0(buf0) kk0 x n01
        rdA(0, 0, a0); rdB(0, 0, b0);
        stage_half(reg_(1,1,0), Bb,         kt1);
        PH_BAR; LGK0; mm(a0, b0, 0); PH_BAR;
        // phase 1: kk0 x n23
        rdA(0, 1, a1);
        stage_half(reg_(1,1,1), Bb + 128*K, kt1);
        PH_BAR; LGK0; mm(a0, b0, 2); PH_BAR;
        // phase 2: kk1 x n01
        rdB(0, 1, b1);
        stage_half(reg_(0,0,0), Ab,         kt2);
        PH_BAR; LGK0; mm(a1, b1, 0); PH_BAR;
        // phase 3: kk1 x n23  [gate: kt1 (buf1) fully landed]
        stage_half(reg_(0,0,1), Ab + 128*K, kt2);
        VM4;
        PH_BAR; LGK0; mm(a1, b1, 2); PH_BAR;
        // phase 4: compute kt1(buf1) kk0 x n01
        rdA(1, 0, a0); rdB(1, 0, b0);
        stage_half(reg_(0,1,0), Bb,         kt2);
        PH_BAR; LGK0; mm(a0, b0, 0); PH_BAR;
        // phase 5: kk0 x n23
        rdA(1, 1, a1);
        stage_half(reg_(0,1,1), Bb + 128*K, kt2);
        PH_BAR; LGK0; mm(a0, b0, 2); PH_BAR;
        // phase 6: kk1 x n01
        rdB(1, 1, b1);
        stage_half(reg_(1,0,0), Ab,         kt3);
        PH_BAR; LGK0; mm(a1, b1, 0); PH_BAR;
        // phase 7: kk1 x n23  [gate: kt2 (next buf0) fully landed]
        stage_half(reg_(1,0,1), Ab + 128*K, kt3);
        VM4;
        PH_BAR; LGK0; mm(a1, b1, 2); PH_BAR;
    }
    asm volatile("s_waitcnt vmcnt(0)" ::: "memory");   // drain wrapped tail loads

    // epilogue
    const int crow = (lane >> 4) * 4, ccol = lane & 15;
    #pragma unroll
    for (int nf = 0; nf < 4; ++nf) {
        size_t col = bn + wn*64 + nf*16 + ccol;
        float bv = bias[col];
        #pragma unroll
        for (int mf = 0; mf < 8; ++mf) {
            #pragma unroll
            for (int r = 0; r < 4; ++r) {
                size_t row = bm + wm*128 + mf*16 + crow + r;
                float v = acc[mf][nf][r] + bv;
                if (MODE == 1) {
                    // tanh-GELU (|err| <= ~1e-3 vs erf; output h is bf16 anyway)
                    float u = 0.7978845608f * (v + 0.044715f*v*v*v);
                    float e = __expf(2.0f*u);
                    float ge = 0.5f*v*(1.0f + (1.0f - 2.0f/(e + 1.0f)));
                    outb[row*(size_t)N + col] = f2bf(ge);
                } else {
                    outf[row*(size_t)N + col] = v + bf2f(resid[row*(size_t)N + col]);
                }
            }
        }
    }
    #undef PH_BAR
    #undef LGK0
    #undef VM4
}

// ------------------------------------------------------- LN2 in-place on d_out
__global__ __launch_bounds__(256) void ln2_kernel(
    float* __restrict__ out, const float* __restrict__ g2, const float* __restrict__ b2)
{
    int row = blockIdx.x;
    int tid = threadIdx.x;
    float4* orow = (float4*)(out + (size_t)row*DDIM);
    float4 y = orow[tid];
    float s  = y.x+y.y+y.z+y.w;
    float ss = y.x*y.x+y.y*y.y+y.z*y.z+y.w*y.w;
    #pragma unroll
    for (int o = 32; o; o >>= 1) { s += __shfl_down(s,o,64); ss += __shfl_down(ss,o,64); }
    __shared__ float red[8];
    if ((tid&63) == 0) { red[tid>>6] = s; red[4+(tid>>6)] = ss; }
    __syncthreads();
    float St = red[0]+red[1]+red[2]+red[3];
    float Sq = red[4]+red[5]+red[6]+red[7];
    float mu = St*(1.0f/DDIM);
    float rs = rsqrtf(Sq*(1.0f/DDIM) - mu*mu + 1e-5f);
    float4 g4 = ((const float4*)g2)[tid];
    float4 bb = ((const float4*)b2)[tid];
    float4 n;
    n.x = (y.x-mu)*rs*g4.x + bb.x;
    n.y = (y.y-mu)*rs*g4.y + bb.y;
    n.z = (y.z-mu)*rs*g4.z + bb.z;
    n.w = (y.w-mu)*rs*g4.w + bb.w;
    orow[tid] = n;
}

// ---------------------------------------------------------------- launch
extern "C" void kernel_launch(void* const* d_in, const int* in_sizes, int n_in,
                              void* d_out, int out_size, void* d_ws, size_t ws_size,
                              hipStream_t stream)
{
    const float* x     = (const float*)d_in[0];
    const float* w_qkv = (const float*)d_in[1];
    const float* w_o   = (const float*)d_in[2];
    const float* w1    = (const float*)d_in[3];
    const float* b1    = (const float*)d_in[4];
    const float* w2    = (const float*)d_in[5];
    const float* b2    = (const float*)d_in[6];
    const float* ln1g  = (const float*)d_in[7];
    const float* ln1b  = (const float*)d_in[8];
    const float* ln2g  = (const float*)d_in[9];
    const float* ln2b  = (const float*)d_in[10];
    float* out = (float*)d_out;
    char* ws = (char*)d_ws;

    unsigned short* x1b = (unsigned short*)(ws);               // 32 MB  x1 bf16
    unsigned short* hb  = (unsigned short*)(ws + 33554432);    // 32 MB  h  bf16
    unsigned short* w1b = (unsigned short*)(ws + 67108864);    // 2 MB
    unsigned short* w2b = (unsigned short*)(ws + 69206016);    // 2 MB
    float* partial = (float*)(ws + 71303168);                  // 512 KB
    float* xsum    = (float*)(ws + 71827456);                  // 16 KB
    float* tvec    = (float*)(ws + 71843840);                  // 16 KB
    float* avec    = (float*)(ws + 71860224);                  // 16 KB

    // allow 128 KB dynamic LDS (host-side attribute; not a stream op)
    (void)hipFuncSetAttribute((const void*)gemm256p8_kernel<1>,
                              hipFuncAttributeMaxDynamicSharedMemorySize, 131072);
    (void)hipFuncSetAttribute((const void*)gemm256p8_kernel<2>,
                              hipFuncAttributeMaxDynamicSharedMemorySize, 131072);

    cast_w_kernel<<<dim3(1024), 256, 0, stream>>>(w1, w2, w1b, w2b);
    colsum_partial_kernel<<<dim3(4, NB, 32), 256, 0, stream>>>(x, partial);
    colsum_reduce_kernel<<<dim3(4, NB), 256, 0, stream>>>(partial, xsum);
    matvec_kernel<<<dim3(64, NB), 256, 0, stream>>>(w_qkv + (size_t)2*DDIM*DDIM, xsum, tvec);
    matvec_kernel<<<dim3(64, NB), 256, 0, stream>>>(w_o, tvec, avec);
    ln1_kernel<<<dim3(MTOT), 256, 0, stream>>>(x, avec, ln1g, ln1b, x1b);
    gemm256p8_kernel<1><<<dim3(256), 512, 131072, stream>>>(
        (const bf16*)x1b, (const bf16*)w1b, b1, nullptr, hb, nullptr);
    gemm256p8_kernel<2><<<dim3(256), 512, 131072, stream>>>(
        (const bf16*)hb, (const bf16*)w2b, b2, x1b, nullptr, out);
    ln2_kernel<<<dim3(MTOT), 256, 0, stream>>>(out, ln2g, ln2b);
}